// Round 3
// baseline (22689.182 us; speedup 1.0000x reference)
//
#include <hip/hip_runtime.h>
#include <hip/hip_bf16.h>

#define BB 32
#define TT 1024
#define EE 256
#define HH 512
#define H3 1536
#define MM (BB*TT)
#define NWG 16
#define EPS_BN 1e-3f

typedef __attribute__((ext_vector_type(8))) short bf16x8;
typedef __attribute__((ext_vector_type(4))) float f32x4;
typedef unsigned long long ull_t;

__device__ __forceinline__ unsigned short f2bf(float f){
  unsigned u = __float_as_uint(f);
  u += 0x7fffu + ((u>>16)&1u);
  return (unsigned short)(u>>16);
}
__device__ __forceinline__ float bf2f(unsigned short u){
  return __uint_as_float(((unsigned)u)<<16);
}

// ---------- fp32 [K,N] -> bf16 [N,K] transpose ----------
__global__ __launch_bounds__(256) void conv_transpose(
    const float* __restrict__ in, unsigned short* __restrict__ out, int K, int N){
  __shared__ float tile[32][33];
  int k0 = blockIdx.x*32, n0 = blockIdx.y*32;
  int tx = threadIdx.x & 31, ty = threadIdx.x >> 5;
  for(int i=ty;i<32;i+=8) tile[i][tx] = in[(size_t)(k0+i)*N + n0 + tx];
  __syncthreads();
  for(int i=ty;i<32;i+=8) out[(size_t)(n0+i)*K + k0 + tx] = f2bf(tile[tx][i]);
}

// ---------- embedding gather -> bf16, t-major [T][B][E] ----------
__global__ __launch_bounds__(256) void gather_emb(
    const int* __restrict__ x, const float* __restrict__ emb,
    unsigned short* __restrict__ y0){
  int i = blockIdx.x*256 + threadIdx.x;
  if(i >= MM*EE/4) return;
  int row = i >> 6;                 // row = t*BB + b
  int c4 = (i & 63) << 2;
  int t = row >> 5, b = row & 31;
  float4 v = *(const float4*)&emb[(size_t)x[b*TT + t]*EE + c4];
  ushort4 o; o.x=f2bf(v.x); o.y=f2bf(v.y); o.z=f2bf(v.z); o.w=f2bf(v.w);
  *(ushort4*)&y0[(size_t)row*EE + c4] = o;
}

// ---------- C[M,N] = A[M,K](bf16) @ BT[N,K](bf16)^T + bias, fp32 out ----------
__global__ __launch_bounds__(256) void gemm_bias(
    const unsigned short* __restrict__ A,
    const unsigned short* __restrict__ BT,
    const float* __restrict__ bias,
    float* __restrict__ C, int Mdim, int Ndim, int Kdim){
  __shared__ __align__(16) unsigned short sA[64][72];
  __shared__ __align__(16) unsigned short sB[64][72];
  int m0 = blockIdx.x*64, n0 = blockIdx.y*64;
  int tid = threadIdx.x, ln = tid & 63, wv = tid >> 6;
  int wm = wv >> 1, wn = wv & 1;
  f32x4 acc[2][2] = {};
  for(int k0=0;k0<Kdim;k0+=64){
    __syncthreads();
    for(int p2=0;p2<2;p2++){
      int idx = (p2*256 + tid)*8;
      int r = idx >> 6, c = idx & 63;
      *(uint4*)&sA[r][c] = *(const uint4*)&A[(size_t)(m0+r)*Kdim + k0 + c];
      *(uint4*)&sB[r][c] = *(const uint4*)&BT[(size_t)(n0+r)*Kdim + k0 + c];
    }
    __syncthreads();
    for(int kk=0;kk<64;kk+=32){
      int kf = kk + ((ln>>4)<<3);
      bf16x8 af[2], bfr[2];
      for(int i=0;i<2;i++){
        af[i]  = *(const bf16x8*)&sA[wm*32 + i*16 + (ln&15)][kf];
        bfr[i] = *(const bf16x8*)&sB[wn*32 + i*16 + (ln&15)][kf];
      }
      for(int mi=0;mi<2;mi++)
        for(int ni=0;ni<2;ni++)
          acc[mi][ni] = __builtin_amdgcn_mfma_f32_16x16x32_bf16(af[mi], bfr[ni], acc[mi][ni], 0,0,0);
    }
  }
  for(int mi=0;mi<2;mi++)
    for(int ni=0;ni<2;ni++){
      int gn = n0 + wn*32 + ni*16 + (ln&15);
      float bs = bias ? bias[gn] : 0.f;
      int gm0 = m0 + wm*32 + mi*16 + ((ln>>4)<<2);
      for(int r2=0;r2<4;r2++)
        C[(size_t)(gm0+r2)*Ndim + gn] = acc[mi][ni][r2] + bs;
    }
}

// ---------- persistent GRU scan: 16 WGs x 4 free-running waves ----------
// No __syncthreads in the time loop. Cross-WG h exchange via relaxed
// agent-scope atomics (per-access coherent, no buffer_inv/wbl2 fences).
__global__ __launch_bounds__(256,1) void gru_scan(
    const float* __restrict__ xproj,        // [C][B][3H] fp32
    const unsigned short* __restrict__ rkT, // [1536][512] bf16
    const float* __restrict__ br,           // [1536]
    float* __restrict__ hstate,             // [B][512] fp32, in/out
    unsigned short* __restrict__ ybf,       // [C][B][512] bf16 (pre-offset)
    float* __restrict__ stats,              // [2][512] accumulated
    unsigned short* Hbuf,                   // [2][B][512] bf16 ping-pong
    int* flags, int C, int wbase, int par0){
  __shared__ __align__(16) unsigned short wsl[96][520];
  __shared__ float sred[2][4][16];
  const int wg = blockIdx.x, c0 = wg*32;
  const int tid = threadIdx.x, ln = tid & 63, wv = tid >> 6;
  const int wm = wv >> 1, nh = wv & 1;

  // stage weight slice (shared by waves, read-only afterwards)
  for(int r = wv; r < 96; r += 4){
    int g = r >> 5, i = r & 31;
    *(uint4*)&wsl[r][ln*8] = *(const uint4*)&rkT[(size_t)(g*HH + c0 + i)*HH + ln*8];
  }
  const int colr = nh*16 + (ln&15);          // channel within WG slice
  const int hrow = wm*16 + (ln&15);          // batch row for A-fragment
  const int br0  = wm*16 + ((ln>>4)<<2);     // first of this thread's 4 batch rows
  const float brz = br[c0+colr], brr = br[HH+c0+colr], brh = br[2*HH+c0+colr];

  // init own h (registers) + publish h(0) into parity-par0 buffer
  float hv[4];
  for(int r2=0;r2<4;r2++){
    hv[r2] = hstate[(br0+r2)*HH + c0 + colr];
    __hip_atomic_store(&Hbuf[(size_t)par0*BB*HH + (br0+r2)*HH + c0 + colr],
                       f2bf(hv[r2]), __ATOMIC_RELAXED, __HIP_MEMORY_SCOPE_AGENT);
  }
  __syncthreads();                                  // weights staged
  asm volatile("s_waitcnt vmcnt(0)" ::: "memory");  // own publishes visible
  if(ln==0) __hip_atomic_store(&flags[wg*4+wv], wbase+1,
                               __ATOMIC_RELAXED, __HIP_MEMORY_SCOPE_AGENT);
  float as = 0.f, aq = 0.f;

  for(int s=0;s<C;s++){
    const int par = (par0 + s) & 1;
    // xproj loads issued early — latency hides under the poll
    float xz[4], xr[4], xh[4];
    {
      const float* xp = &xproj[(size_t)s*BB*H3];
      for(int r2=0;r2<4;r2++){
        int b = br0 + r2;
        xz[r2] = xp[b*H3 + c0 + colr];
        xr[r2] = xp[b*H3 + HH + c0 + colr];
        xh[r2] = xp[b*H3 + 2*HH + c0 + colr];
      }
    }
    // wait until all 64 waves have published h(s) — relaxed coherent loads
    {
      const int need = wbase + s + 1;
      int guard = 0; bool done = false;
      while(!done && guard < 100000){
        int v = __hip_atomic_load(&flags[ln], __ATOMIC_RELAXED, __HIP_MEMORY_SCOPE_AGENT);
        done = __all(v >= need) != 0;
        if(!done){ __builtin_amdgcn_s_sleep(1); guard++; }
      }
    }
    __builtin_amdgcn_sched_barrier(0);
    // gather this wave's A-fragments straight to registers (coherent 8B loads)
    ull_t hb[32];
    {
      const ull_t* hsrc = (const ull_t*)&Hbuf[(size_t)par*BB*HH + (size_t)hrow*HH];
      #pragma unroll
      for(int kk=0;kk<16;kk++){
        int off = (kk*32 + ((ln>>4)<<3)) >> 2;   // ull index
        hb[2*kk]   = __hip_atomic_load(hsrc+off,   __ATOMIC_RELAXED, __HIP_MEMORY_SCOPE_AGENT);
        hb[2*kk+1] = __hip_atomic_load(hsrc+off+1, __ATOMIC_RELAXED, __HIP_MEMORY_SCOPE_AGENT);
      }
    }
    f32x4 acc[3] = {};
    #pragma unroll
    for(int kk=0;kk<16;kk++){
      union { ull_t u[2]; bf16x8 v; } af;
      af.u[0] = hb[2*kk]; af.u[1] = hb[2*kk+1];
      int kf = kk*32 + ((ln>>4)<<3);
      #pragma unroll
      for(int g=0;g<3;g++){
        bf16x8 bfr = *(const bf16x8*)&wsl[g*32 + colr][kf];
        acc[g] = __builtin_amdgcn_mfma_f32_16x16x32_bf16(af.v, bfr, acc[g], 0,0,0);
      }
    }
    // gates + state update + publish
    for(int r2=0;r2<4;r2++){
      int brow = br0 + r2;
      float z  = 1.f/(1.f + __expf(-(xz[r2] + acc[0][r2] + brz)));
      float rr = 1.f/(1.f + __expf(-(xr[r2] + acc[1][r2] + brr)));
      float cd = fmaxf(xh[r2] + rr*(acc[2][r2] + brh), 0.f);
      float hn = z*hv[r2] + (1.f - z)*cd;
      hv[r2] = hn;
      ybf[((size_t)s*BB + brow)*HH + c0 + colr] = f2bf(hn);
      __hip_atomic_store(&Hbuf[(size_t)(1-par)*BB*HH + brow*HH + c0 + colr],
                         f2bf(hn), __ATOMIC_RELAXED, __HIP_MEMORY_SCOPE_AGENT);
      as += hn; aq += hn*hn;
    }
    asm volatile("s_waitcnt vmcnt(0)" ::: "memory");  // publishes visible
    if(ln==0) __hip_atomic_store(&flags[wg*4+wv], wbase+s+2,
                                 __ATOMIC_RELAXED, __HIP_MEMORY_SCOPE_AGENT);
  }
  // final state
  for(int r2=0;r2<4;r2++) hstate[(br0+r2)*HH + c0 + colr] = hv[r2];
  // BN stats reduce (channels WG-exclusive)
  as += __shfl_xor(as, 16); as += __shfl_xor(as, 32);
  aq += __shfl_xor(aq, 16); aq += __shfl_xor(aq, 32);
  if((ln>>4)==0){ sred[0][wv][ln&15] = as; sred[1][wv][ln&15] = aq; }
  __syncthreads();
  if(tid < 32){
    int nh2 = tid >> 4, cc = tid & 15;
    stats[c0 + tid]      += sred[0][nh2][cc] + sred[0][2+nh2][cc];
    stats[HH + c0 + tid] += sred[1][nh2][cc] + sred[1][2+nh2][cc];
  }
}

// ---------- BN prep: stats -> scale/shift ----------
__global__ void bn_prep(const float* __restrict__ stats,
                        const float* __restrict__ gamma, const float* __restrict__ beta,
                        float* __restrict__ scsh){
  int c = blockIdx.x*256 + threadIdx.x;
  if(c >= HH) return;
  const float inv = 1.f/(float)MM;
  float mean = stats[c]*inv;
  float var  = stats[HH+c]*inv - mean*mean;
  float s = gamma[c]*rsqrtf(var + EPS_BN);
  scsh[c] = s; scsh[HH+c] = beta[c] - mean*s;
}

// ---------- fold BN into next GEMM ----------
__global__ __launch_bounds__(256) void kscale(
    const unsigned short* __restrict__ kT, const float* __restrict__ scsh,
    const float* __restrict__ bias, unsigned short* __restrict__ kTs,
    float* __restrict__ badj){
  int n = blockIdx.x*4 + (threadIdx.x >> 6);
  int ln = threadIdx.x & 63;
  int k = ln*8;
  uint4 v = *(const uint4*)&kT[(size_t)n*HH + k];
  unsigned short* pv = (unsigned short*)&v;
  unsigned short ov[8];
  float acc = 0.f;
  for(int j=0;j<8;j++){
    float f = bf2f(pv[j]);
    acc += scsh[HH + k + j] * f;
    ov[j] = f2bf(f * scsh[k + j]);
  }
  *(uint4*)&kTs[(size_t)n*HH + k] = *(uint4*)ov;
  for(int d=1; d<64; d<<=1) acc += __shfl_xor(acc, d);
  if(ln==0) badj[n] = bias[n] + acc;
}

// ---------- final BN + transpose to [B][T][H] fp32 ----------
__global__ __launch_bounds__(256) void final_out(
    const unsigned short* __restrict__ ybf, const float* __restrict__ scsh,
    float* __restrict__ out){
  int row = blockIdx.x*4 + (threadIdx.x >> 6);   // t*BB + b
  int ln = threadIdx.x & 63;
  int t = row >> 5, b = row & 31;
  int k = ln*8;
  uint4 v = *(const uint4*)&ybf[(size_t)row*HH + k];
  unsigned short* pv = (unsigned short*)&v;
  float o[8];
  for(int j=0;j<8;j++) o[j] = bf2f(pv[j])*scsh[k+j] + scsh[HH+k+j];
  float4* dst = (float4*)&out[((size_t)b*TT + t)*HH + k];
  dst[0] = make_float4(o[0],o[1],o[2],o[3]);
  dst[1] = make_float4(o[4],o[5],o[6],o[7]);
}

__global__ void copy_f32(const float* __restrict__ in, float* __restrict__ out, int n){
  int i = blockIdx.x*blockDim.x + threadIdx.x;
  if(i<n) out[i] = in[i];
}

extern "C" void kernel_launch(void* const* d_in, const int* in_sizes, int n_in,
                              void* d_out, int out_size, void* d_ws, size_t ws_size,
                              hipStream_t stream){
  const int*   x      = (const int*)d_in[0];
  const float* emb    = (const float*)d_in[1];
  const float* k0     = (const float*)d_in[2];
  const float* rk0    = (const float*)d_in[3];
  const float* b0     = (const float*)d_in[4];
  const float* krest  = (const float*)d_in[5];
  const float* rkrest = (const float*)d_in[6];
  const float* brest  = (const float*)d_in[7];
  const float* gammas = (const float*)d_in[8];
  const float* betas  = (const float*)d_in[9];
  float* out_y = (float*)d_out;
  float* out_state = out_y + (size_t)MM*HH;

  char* p = (char*)d_ws;
  auto alloc = [&](size_t bytes)->void*{ void* r = p; p += (bytes + 255) & ~(size_t)255; return r; };
  unsigned short* ybf  = (unsigned short*)alloc((size_t)MM*HH*2);   // [T][B][H]
  unsigned short* y0bf = (unsigned short*)alloc((size_t)MM*EE*2);   // [T][B][E]
  unsigned short* kT0  = (unsigned short*)alloc((size_t)H3*EE*2);
  unsigned short* kT1  = (unsigned short*)alloc((size_t)H3*HH*2);
  unsigned short* kT2  = (unsigned short*)alloc((size_t)H3*HH*2);
  unsigned short* rkT0 = (unsigned short*)alloc((size_t)H3*HH*2);
  unsigned short* rkT1 = (unsigned short*)alloc((size_t)H3*HH*2);
  unsigned short* rkT2 = (unsigned short*)alloc((size_t)H3*HH*2);
  unsigned short* kTs  = (unsigned short*)alloc((size_t)H3*HH*2);
  float* badj   = (float*)alloc(H3*4);
  float* scsh   = (float*)alloc(2*HH*4);
  float* stats  = (float*)alloc(2*HH*4);
  float* hstate = (float*)alloc((size_t)BB*HH*4);
  unsigned short* Hbuf = (unsigned short*)alloc((size_t)2*BB*HH*2);
  int* flags = (int*)alloc(NWG*4*4);   // per-wave flags: 64 ints
  size_t fixed_bytes = (size_t)(p - (char*)d_ws);

  int C = 64;
  const int cands[4] = {1024, 512, 256, 128};
  for(int i=0;i<4;i++){
    if(fixed_bytes + (size_t)cands[i]*BB*H3*4 <= ws_size){ C = cands[i]; break; }
  }
  float* xproj = (float*)alloc((size_t)C*BB*H3*4);   // [C][B][3H]
  const int NC = TT / C;

  hipMemsetAsync(flags, 0, NWG*4*4, stream);
  hipMemsetAsync(hstate, 0, (size_t)BB*HH*4, stream);

  conv_transpose<<<dim3(EE/32, H3/32), 256, 0, stream>>>(k0, kT0, EE, H3);
  conv_transpose<<<dim3(HH/32, H3/32), 256, 0, stream>>>(krest, kT1, HH, H3);
  conv_transpose<<<dim3(HH/32, H3/32), 256, 0, stream>>>(krest + (size_t)HH*H3, kT2, HH, H3);
  conv_transpose<<<dim3(HH/32, H3/32), 256, 0, stream>>>(rk0, rkT0, HH, H3);
  conv_transpose<<<dim3(HH/32, H3/32), 256, 0, stream>>>(rkrest, rkT1, HH, H3);
  conv_transpose<<<dim3(HH/32, H3/32), 256, 0, stream>>>(rkrest + (size_t)HH*H3, rkT2, HH, H3);
  gather_emb<<<(MM*EE/4 + 255)/256, 256, 0, stream>>>(x, emb, y0bf);

  for(int L=0; L<3; L++){
    hipMemsetAsync(stats, 0, 2*HH*4, stream);
    const unsigned short* A; const unsigned short* BT; const float* bias;
    const unsigned short* rk; const float* rbias; int Kd;
    if(L == 0){
      A = y0bf; BT = kT0; bias = b0; rk = rkT0; rbias = b0 + H3; Kd = EE;
    } else {
      const unsigned short* kTn = (L==1) ? kT1 : kT2;
      const float* bn_bias = (L==1) ? brest : brest + 2*H3;
      kscale<<<H3/4, 256, 0, stream>>>(kTn, scsh, bn_bias, kTs, badj);
      A = ybf; BT = kTs; bias = badj; Kd = HH;
      rk = (L==1) ? rkT1 : rkT2;
      rbias = (L==1) ? brest + H3 : brest + 3*H3;
    }
    for(int c=0;c<NC;c++){
      int t0 = c*C;
      gemm_bias<<<dim3(C*BB/64, H3/64), 256, 0, stream>>>(
          A + (size_t)t0*BB*Kd, BT, bias, xproj, C*BB, H3, Kd);
      gru_scan<<<NWG, 256, 0, stream>>>(
          xproj, rk, rbias, hstate, ybf + (size_t)t0*BB*HH,
          stats, Hbuf, flags, C, L*(TT+1) + t0, t0 & 1);
    }
    bn_prep<<<2, 256, 0, stream>>>(stats, gammas + L*HH, betas + L*HH, scsh);
  }
  final_out<<<MM/4, 256, 0, stream>>>(ybf, scsh, out_y);
  copy_f32<<<64, 256, 0, stream>>>(hstate, out_state, BB*HH);
}

// Round 4
// 12279.198 us; speedup vs baseline: 1.8478x; 1.8478x over previous
//
#include <hip/hip_runtime.h>
#include <hip/hip_bf16.h>

#define BB 32
#define TT 1024
#define EE 256
#define HH 512
#define H3 1536
#define MM (BB*TT)
#define NWG 16
#define EPS_BN 1e-3f

typedef __attribute__((ext_vector_type(8))) short bf16x8;
typedef __attribute__((ext_vector_type(4))) float f32x4;

__device__ __forceinline__ unsigned short f2bf(float f){
  unsigned u = __float_as_uint(f);
  u += 0x7fffu + ((u>>16)&1u);
  return (unsigned short)(u>>16);
}
__device__ __forceinline__ float bf2f(unsigned short u){
  return __uint_as_float(((unsigned)u)<<16);
}
// coherent (L3-point) 16B load / 2B store — bypass non-coherent L1/L2
__device__ __forceinline__ uint4 ld16_coh(const void* p){
  uint4 r;
  asm volatile("global_load_dwordx4 %0, %1, off sc0 sc1" : "=v"(r) : "v"(p) : "memory");
  return r;
}
__device__ __forceinline__ void st2_coh(unsigned short* p, unsigned short v){
  unsigned w = v;
  asm volatile("global_store_short %0, %1, off sc0 sc1" :: "v"(p), "v"(w) : "memory");
}

// ---------- fp32 [K,N] -> bf16 [N,K] transpose ----------
__global__ __launch_bounds__(256) void conv_transpose(
    const float* __restrict__ in, unsigned short* __restrict__ out, int K, int N){
  __shared__ float tile[32][33];
  int k0 = blockIdx.x*32, n0 = blockIdx.y*32;
  int tx = threadIdx.x & 31, ty = threadIdx.x >> 5;
  for(int i=ty;i<32;i+=8) tile[i][tx] = in[(size_t)(k0+i)*N + n0 + tx];
  __syncthreads();
  for(int i=ty;i<32;i+=8) out[(size_t)(n0+i)*K + k0 + tx] = f2bf(tile[tx][i]);
}

// ---------- embedding gather -> bf16, t-major [T][B][E] ----------
__global__ __launch_bounds__(256) void gather_emb(
    const int* __restrict__ x, const float* __restrict__ emb,
    unsigned short* __restrict__ y0){
  int i = blockIdx.x*256 + threadIdx.x;
  if(i >= MM*EE/4) return;
  int row = i >> 6;                 // row = t*BB + b
  int c4 = (i & 63) << 2;
  int t = row >> 5, b = row & 31;
  float4 v = *(const float4*)&emb[(size_t)x[b*TT + t]*EE + c4];
  ushort4 o; o.x=f2bf(v.x); o.y=f2bf(v.y); o.z=f2bf(v.z); o.w=f2bf(v.w);
  *(ushort4*)&y0[(size_t)row*EE + c4] = o;
}

// ---------- C[M,N] = A[M,K](bf16) @ BT[N,K](bf16)^T + bias, fp32 out ----------
__global__ __launch_bounds__(256) void gemm_bias(
    const unsigned short* __restrict__ A,
    const unsigned short* __restrict__ BT,
    const float* __restrict__ bias,
    float* __restrict__ C, int Mdim, int Ndim, int Kdim){
  __shared__ __align__(16) unsigned short sA[64][72];
  __shared__ __align__(16) unsigned short sB[64][72];
  int m0 = blockIdx.x*64, n0 = blockIdx.y*64;
  int tid = threadIdx.x, ln = tid & 63, wv = tid >> 6;
  int wm = wv >> 1, wn = wv & 1;
  f32x4 acc[2][2] = {};
  for(int k0=0;k0<Kdim;k0+=64){
    __syncthreads();
    for(int p2=0;p2<2;p2++){
      int idx = (p2*256 + tid)*8;
      int r = idx >> 6, c = idx & 63;
      *(uint4*)&sA[r][c] = *(const uint4*)&A[(size_t)(m0+r)*Kdim + k0 + c];
      *(uint4*)&sB[r][c] = *(const uint4*)&BT[(size_t)(n0+r)*Kdim + k0 + c];
    }
    __syncthreads();
    for(int kk=0;kk<64;kk+=32){
      int kf = kk + ((ln>>4)<<3);
      bf16x8 af[2], bfr[2];
      for(int i=0;i<2;i++){
        af[i]  = *(const bf16x8*)&sA[wm*32 + i*16 + (ln&15)][kf];
        bfr[i] = *(const bf16x8*)&sB[wn*32 + i*16 + (ln&15)][kf];
      }
      for(int mi=0;mi<2;mi++)
        for(int ni=0;ni<2;ni++)
          acc[mi][ni] = __builtin_amdgcn_mfma_f32_16x16x32_bf16(af[mi], bfr[ni], acc[mi][ni], 0,0,0);
    }
  }
  for(int mi=0;mi<2;mi++)
    for(int ni=0;ni<2;ni++){
      int gn = n0 + wn*32 + ni*16 + (ln&15);
      float bs = bias ? bias[gn] : 0.f;
      int gm0 = m0 + wm*32 + mi*16 + ((ln>>4)<<2);
      for(int r2=0;r2<4;r2++)
        C[(size_t)(gm0+r2)*Ndim + gn] = acc[mi][ni][r2] + bs;
    }
}

// ---------- persistent GRU scan: 16 WGs, wave0 polls, LDS-staged h ----------
// All cross-WG traffic via sc0/sc1 per-access coherent ops. No threadfence,
// no acquire fences => no buffer_inv / buffer_wbl2 in the time loop.
// Hbuf layout: [2 parity][NWG][B][32] bf16.
__global__ __launch_bounds__(256,1) void gru_scan(
    const float* __restrict__ xproj,        // [C][B][3H] fp32
    const unsigned short* __restrict__ rkT, // [1536][512] bf16
    const float* __restrict__ br,           // [1536]
    float* __restrict__ hstate,             // [B][512] fp32, in/out
    unsigned short* __restrict__ ybf,       // [C][B][512] bf16 (pre-offset)
    float* __restrict__ stats,              // [2][512] accumulated
    unsigned short* Hbuf,                   // [2][NWG][B][32] bf16 ping-pong
    int* flags, int C, int wbase, int par0){
  __shared__ __align__(16) unsigned short wsl[96][520];
  __shared__ __align__(16) unsigned short hlds[32][520];
  __shared__ float sred[2][4][16];
  const int wg = blockIdx.x, c0 = wg*32;
  const int tid = threadIdx.x, ln = tid & 63, wv = tid >> 6;
  const int wm = wv >> 1, nh = wv & 1;

  for(int r = wv; r < 96; r += 4){
    int g = r >> 5, i = r & 31;
    *(uint4*)&wsl[r][ln*8] = *(const uint4*)&rkT[(size_t)(g*HH + c0 + i)*HH + ln*8];
  }
  const int colr = nh*16 + (ln&15);
  const int br0  = wm*16 + ((ln>>4)<<2);
  const float brz = br[c0+colr], brr = br[HH+c0+colr], brh = br[2*HH+c0+colr];

  // init own h (registers) + publish h(0) into parity-par0 buffer
  float hv[4];
  for(int r2=0;r2<4;r2++){
    hv[r2] = hstate[(br0+r2)*HH + c0 + colr];
    st2_coh(&Hbuf[(((size_t)par0*NWG + wg)*BB + (br0+r2))*32 + colr], f2bf(hv[r2]));
  }
  __syncthreads();
  asm volatile("s_waitcnt vmcnt(0)" ::: "memory");
  if(tid==0) __hip_atomic_store(&flags[wg], wbase+1, __ATOMIC_RELAXED, __HIP_MEMORY_SCOPE_AGENT);
  float as = 0.f, aq = 0.f;

  for(int s=0;s<C;s++){
    const int par = (par0 + s) & 1;
    // xproj loads issued early — latency hides under the poll
    float xz[4], xr[4], xh[4];
    {
      const float* xp = &xproj[(size_t)s*BB*H3];
      for(int r2=0;r2<4;r2++){
        int b = br0 + r2;
        xz[r2] = xp[b*H3 + c0 + colr];
        xr[r2] = xp[b*H3 + HH + c0 + colr];
        xh[r2] = xp[b*H3 + 2*HH + c0 + colr];
      }
    }
    // wave 0 polls the 16 per-WG flags (relaxed, coherent)
    if(wv==0){
      const int need = wbase + s + 1;
      int guard = 0; bool done = false;
      while(!done && guard < 200000){
        int v = (ln < NWG) ? __hip_atomic_load(&flags[ln], __ATOMIC_RELAXED, __HIP_MEMORY_SCOPE_AGENT)
                           : 0x7fffffff;
        done = __all(v >= need) != 0;
        if(!done){ __builtin_amdgcn_s_sleep(1); guard++; }
      }
    }
    __syncthreads();
    // stage h(s): 32KB contiguous, coherent 16B loads -> LDS
    {
      const unsigned short* src = &Hbuf[(size_t)par*NWG*BB*32];
      uint4 hb[8];
      #pragma unroll
      for(int j=0;j<8;j++){
        int i = (j*256 + tid)*8;             // short index
        hb[j] = ld16_coh(&src[i]);
      }
      asm volatile("s_waitcnt vmcnt(0)" ::: "memory");
      __builtin_amdgcn_sched_barrier(0);
      #pragma unroll
      for(int j=0;j<8;j++){
        int i = (j*256 + tid)*8;
        int cc = i & 31, b = (i >> 5) & 31, sw = i >> 10;
        *(uint4*)&hlds[b][sw*32 + cc] = hb[j];
      }
    }
    __syncthreads();
    // inner = h @ rk (slice), fp32 accum
    f32x4 acc[3] = {};
    #pragma unroll
    for(int kk=0;kk<HH;kk+=32){
      int kf = kk + ((ln>>4)<<3);
      bf16x8 af = *(const bf16x8*)&hlds[wm*16 + (ln&15)][kf];
      #pragma unroll
      for(int g=0;g<3;g++){
        bf16x8 bfr = *(const bf16x8*)&wsl[g*32 + colr][kf];
        acc[g] = __builtin_amdgcn_mfma_f32_16x16x32_bf16(af, bfr, acc[g], 0,0,0);
      }
    }
    // gates + state update + publish
    for(int r2=0;r2<4;r2++){
      int brow = br0 + r2;
      float z  = 1.f/(1.f + __expf(-(xz[r2] + acc[0][r2] + brz)));
      float rr = 1.f/(1.f + __expf(-(xr[r2] + acc[1][r2] + brr)));
      float cd = fmaxf(xh[r2] + rr*(acc[2][r2] + brh), 0.f);
      float hn = z*hv[r2] + (1.f - z)*cd;
      hv[r2] = hn;
      ybf[((size_t)s*BB + brow)*HH + c0 + colr] = f2bf(hn);
      st2_coh(&Hbuf[(((size_t)(1-par)*NWG + wg)*BB + brow)*32 + colr], f2bf(hn));
      as += hn; aq += hn*hn;
    }
    asm volatile("s_waitcnt vmcnt(0)" ::: "memory");
    if(tid==0) __hip_atomic_store(&flags[wg], wbase+s+2, __ATOMIC_RELAXED, __HIP_MEMORY_SCOPE_AGENT);
  }
  // final state
  for(int r2=0;r2<4;r2++) hstate[(br0+r2)*HH + c0 + colr] = hv[r2];
  // BN stats reduce (channels WG-exclusive)
  as += __shfl_xor(as, 16); as += __shfl_xor(as, 32);
  aq += __shfl_xor(aq, 16); aq += __shfl_xor(aq, 32);
  if((ln>>4)==0){ sred[0][wv][ln&15] = as; sred[1][wv][ln&15] = aq; }
  __syncthreads();
  if(tid < 32){
    int nh2 = tid >> 4, cc = tid & 15;
    stats[c0 + tid]      += sred[0][nh2][cc] + sred[0][2+nh2][cc];
    stats[HH + c0 + tid] += sred[1][nh2][cc] + sred[1][2+nh2][cc];
  }
}

// ---------- BN prep: stats -> scale/shift ----------
__global__ void bn_prep(const float* __restrict__ stats,
                        const float* __restrict__ gamma, const float* __restrict__ beta,
                        float* __restrict__ scsh){
  int c = blockIdx.x*256 + threadIdx.x;
  if(c >= HH) return;
  const float inv = 1.f/(float)MM;
  float mean = stats[c]*inv;
  float var  = stats[HH+c]*inv - mean*mean;
  float s = gamma[c]*rsqrtf(var + EPS_BN);
  scsh[c] = s; scsh[HH+c] = beta[c] - mean*s;
}

// ---------- fold BN into next GEMM ----------
__global__ __launch_bounds__(256) void kscale(
    const unsigned short* __restrict__ kT, const float* __restrict__ scsh,
    const float* __restrict__ bias, unsigned short* __restrict__ kTs,
    float* __restrict__ badj){
  int n = blockIdx.x*4 + (threadIdx.x >> 6);
  int ln = threadIdx.x & 63;
  int k = ln*8;
  uint4 v = *(const uint4*)&kT[(size_t)n*HH + k];
  unsigned short* pv = (unsigned short*)&v;
  unsigned short ov[8];
  float acc = 0.f;
  for(int j=0;j<8;j++){
    float f = bf2f(pv[j]);
    acc += scsh[HH + k + j] * f;
    ov[j] = f2bf(f * scsh[k + j]);
  }
  *(uint4*)&kTs[(size_t)n*HH + k] = *(uint4*)ov;
  for(int d=1; d<64; d<<=1) acc += __shfl_xor(acc, d);
  if(ln==0) badj[n] = bias[n] + acc;
}

// ---------- final BN + transpose to [B][T][H] fp32 ----------
__global__ __launch_bounds__(256) void final_out(
    const unsigned short* __restrict__ ybf, const float* __restrict__ scsh,
    float* __restrict__ out){
  int row = blockIdx.x*4 + (threadIdx.x >> 6);   // t*BB + b
  int ln = threadIdx.x & 63;
  int t = row >> 5, b = row & 31;
  int k = ln*8;
  uint4 v = *(const uint4*)&ybf[(size_t)row*HH + k];
  unsigned short* pv = (unsigned short*)&v;
  float o[8];
  for(int j=0;j<8;j++) o[j] = bf2f(pv[j])*scsh[k+j] + scsh[HH+k+j];
  float4* dst = (float4*)&out[((size_t)b*TT + t)*HH + k];
  dst[0] = make_float4(o[0],o[1],o[2],o[3]);
  dst[1] = make_float4(o[4],o[5],o[6],o[7]);
}

__global__ void copy_f32(const float* __restrict__ in, float* __restrict__ out, int n){
  int i = blockIdx.x*blockDim.x + threadIdx.x;
  if(i<n) out[i] = in[i];
}

extern "C" void kernel_launch(void* const* d_in, const int* in_sizes, int n_in,
                              void* d_out, int out_size, void* d_ws, size_t ws_size,
                              hipStream_t stream){
  const int*   x      = (const int*)d_in[0];
  const float* emb    = (const float*)d_in[1];
  const float* k0     = (const float*)d_in[2];
  const float* rk0    = (const float*)d_in[3];
  const float* b0     = (const float*)d_in[4];
  const float* krest  = (const float*)d_in[5];
  const float* rkrest = (const float*)d_in[6];
  const float* brest  = (const float*)d_in[7];
  const float* gammas = (const float*)d_in[8];
  const float* betas  = (const float*)d_in[9];
  float* out_y = (float*)d_out;
  float* out_state = out_y + (size_t)MM*HH;

  char* p = (char*)d_ws;
  auto alloc = [&](size_t bytes)->void*{ void* r = p; p += (bytes + 255) & ~(size_t)255; return r; };
  unsigned short* ybf  = (unsigned short*)alloc((size_t)MM*HH*2);   // [T][B][H]
  unsigned short* y0bf = (unsigned short*)alloc((size_t)MM*EE*2);   // [T][B][E]
  unsigned short* kT0  = (unsigned short*)alloc((size_t)H3*EE*2);
  unsigned short* kT1  = (unsigned short*)alloc((size_t)H3*HH*2);
  unsigned short* kT2  = (unsigned short*)alloc((size_t)H3*HH*2);
  unsigned short* rkT0 = (unsigned short*)alloc((size_t)H3*HH*2);
  unsigned short* rkT1 = (unsigned short*)alloc((size_t)H3*HH*2);
  unsigned short* rkT2 = (unsigned short*)alloc((size_t)H3*HH*2);
  unsigned short* kTs  = (unsigned short*)alloc((size_t)H3*HH*2);
  float* badj   = (float*)alloc(H3*4);
  float* scsh   = (float*)alloc(2*HH*4);
  float* stats  = (float*)alloc(2*HH*4);
  float* hstate = (float*)alloc((size_t)BB*HH*4);
  unsigned short* Hbuf = (unsigned short*)alloc((size_t)2*NWG*BB*32*2);
  int* flags = (int*)alloc(NWG*4);
  size_t fixed_bytes = (size_t)(p - (char*)d_ws);

  int C = 64;
  const int cands[4] = {1024, 512, 256, 128};
  for(int i=0;i<4;i++){
    if(fixed_bytes + (size_t)cands[i]*BB*H3*4 <= ws_size){ C = cands[i]; break; }
  }
  float* xproj = (float*)alloc((size_t)C*BB*H3*4);   // [C][B][3H]
  const int NC = TT / C;

  hipMemsetAsync(flags, 0, NWG*4, stream);
  hipMemsetAsync(hstate, 0, (size_t)BB*HH*4, stream);

  conv_transpose<<<dim3(EE/32, H3/32), 256, 0, stream>>>(k0, kT0, EE, H3);
  conv_transpose<<<dim3(HH/32, H3/32), 256, 0, stream>>>(krest, kT1, HH, H3);
  conv_transpose<<<dim3(HH/32, H3/32), 256, 0, stream>>>(krest + (size_t)HH*H3, kT2, HH, H3);
  conv_transpose<<<dim3(HH/32, H3/32), 256, 0, stream>>>(rk0, rkT0, HH, H3);
  conv_transpose<<<dim3(HH/32, H3/32), 256, 0, stream>>>(rkrest, rkT1, HH, H3);
  conv_transpose<<<dim3(HH/32, H3/32), 256, 0, stream>>>(rkrest + (size_t)HH*H3, rkT2, HH, H3);
  gather_emb<<<(MM*EE/4 + 255)/256, 256, 0, stream>>>(x, emb, y0bf);

  for(int L=0; L<3; L++){
    hipMemsetAsync(stats, 0, 2*HH*4, stream);
    const unsigned short* A; const unsigned short* BT; const float* bias;
    const unsigned short* rk; const float* rbias; int Kd;
    if(L == 0){
      A = y0bf; BT = kT0; bias = b0; rk = rkT0; rbias = b0 + H3; Kd = EE;
    } else {
      const unsigned short* kTn = (L==1) ? kT1 : kT2;
      const float* bn_bias = (L==1) ? brest : brest + 2*H3;
      kscale<<<H3/4, 256, 0, stream>>>(kTn, scsh, bn_bias, kTs, badj);
      A = ybf; BT = kTs; bias = badj; Kd = HH;
      rk = (L==1) ? rkT1 : rkT2;
      rbias = (L==1) ? brest + H3 : brest + 3*H3;
    }
    for(int c=0;c<NC;c++){
      int t0 = c*C;
      gemm_bias<<<dim3(C*BB/64, H3/64), 256, 0, stream>>>(
          A + (size_t)t0*BB*Kd, BT, bias, xproj, C*BB, H3, Kd);
      gru_scan<<<NWG, 256, 0, stream>>>(
          xproj, rk, rbias, hstate, ybf + (size_t)t0*BB*HH,
          stats, Hbuf, flags, C, L*(TT+1) + t0, 0);
    }
    bn_prep<<<2, 256, 0, stream>>>(stats, gammas + L*HH, betas + L*HH, scsh);
  }
  final_out<<<MM/4, 256, 0, stream>>>(ybf, scsh, out_y);
  copy_f32<<<64, 256, 0, stream>>>(hstate, out_state, BB*HH);
}